// Round 14
// baseline (126.697 us; speedup 1.0000x reference)
//
#include <hip/hip_runtime.h>
#include <cstdint>
#include <cstddef>

#define BB 4
#define CC 256
#define NN 4096
#define CO 32

typedef __attribute__((ext_vector_type(8))) short bf8;
typedef __attribute__((ext_vector_type(4))) float f4;
typedef __attribute__((ext_vector_type(16))) float f16f;
typedef __attribute__((ext_vector_type(2))) unsigned int u32x2;

#define AS1 __attribute__((address_space(1)))
#define AS3 __attribute__((address_space(3)))

__device__ __forceinline__ unsigned short f2bf(float f) {
    union { float f; unsigned int u; } c; c.f = f;
    unsigned int r = c.u + 0x7FFFu + ((c.u >> 16) & 1u);
    return (unsigned short)(r >> 16);
}
__device__ __forceinline__ float bf2f(unsigned short b) {
    union { unsigned int u; float f; } c; c.u = ((unsigned int)b) << 16;
    return c.f;
}
__device__ __forceinline__ unsigned int cvt_pk_bf16(float a, float b) {
    unsigned int r;
    asm("v_cvt_pk_bf16_f32 %0, %1, %2" : "=v"(r) : "v"(a), "v"(b));
    return r;
}

// ---------------- kernel 1: fused prep (transpose + QK-proj + V-proj) -------
__global__ __launch_bounds__(512, 2) void k_prep(
        const float* __restrict__ x,
        const float* __restrict__ wq, const float* __restrict__ bq,
        const float* __restrict__ wk, const float* __restrict__ bk,
        const float* __restrict__ wv, const float* __restrict__ bv,
        unsigned short* __restrict__ q_hi, unsigned short* __restrict__ q_lo,
        unsigned short* __restrict__ k_hi, unsigned short* __restrict__ k_lo,
        unsigned short* __restrict__ vws) {
    __shared__ float xT[64 * 256];   // (i,c) at i*256 + ((c>>2)^(i&7))*4 + (c&3)
    int blk = blockIdx.x;
    int it = blk & 63, b = blk >> 6;
    int i0 = it * 64;
    int tid = threadIdx.x, w = tid >> 6, lane = tid & 63;
    int lr = lane & 15, lg = lane >> 4;

    // phase 1: load + swizzled transpose
    {
        const float* xp = x + (size_t)b * CC * NN + i0;
        int cl = tid >> 4;            // 0..31
        int il = (tid & 15) * 4;      // 0..60
#pragma unroll
        for (int pass = 0; pass < 8; ++pass) {
            int c = pass * 32 + cl;
            f4 v = *(const f4*)(xp + (size_t)c * NN + il);
#pragma unroll
            for (int jj = 0; jj < 4; ++jj) {
                int i = il + jj;
                xT[i * 256 + (((c >> 2) ^ (i & 7)) << 2) + (c & 3)] = v[jj];
            }
        }
    }
    __syncthreads();

    if (w < 4) {
        // ---- Q/K projection, wave w -> local i rows [w*16, w*16+16) ----
        f4 acc[4] = {};
        for (int ks = 0; ks < 8; ++ks) {
            int i = w * 16 + lr;
            int kc = ks * 32 + lg * 8;
            f4 xa = *(const f4*)&xT[i * 256 + (((kc >> 2) ^ (i & 7)) << 2)];
            f4 xb = *(const f4*)&xT[i * 256 + ((((kc >> 2) + 1) ^ (i & 7)) << 2)];
            bf8 ahi, alo;
#pragma unroll
            for (int e = 0; e < 8; ++e) {
                float f = (e < 4) ? xa[e] : xb[e - 4];
                unsigned short hh = f2bf(f);
                ahi[e] = (short)hh;
                alo[e] = (short)f2bf(f - bf2f(hh));
            }
#pragma unroll
            for (int u = 0; u < 4; ++u) {
                int o = u * 16 + lr;
                const float* wrow = (u < 2) ? (wq + (size_t)o * CC)
                                            : (wk + (size_t)(o - 32) * CC);
                bf8 bhi, blo;
#pragma unroll
                for (int e = 0; e < 8; ++e) {
                    float wvv = wrow[ks * 32 + lg * 8 + e];
                    unsigned short hh = f2bf(wvv);
                    bhi[e] = (short)hh;
                    blo[e] = (short)f2bf(wvv - bf2f(hh));
                }
                acc[u] = __builtin_amdgcn_mfma_f32_16x16x32_bf16(alo, bhi, acc[u], 0, 0, 0);
                acc[u] = __builtin_amdgcn_mfma_f32_16x16x32_bf16(ahi, blo, acc[u], 0, 0, 0);
                acc[u] = __builtin_amdgcn_mfma_f32_16x16x32_bf16(ahi, bhi, acc[u], 0, 0, 0);
            }
        }
#pragma unroll
        for (int u = 0; u < 4; ++u) {
            int o = u * 16 + lr;
            float bias = (u < 2) ? bq[o] : bk[o - 32];
#pragma unroll
            for (int r = 0; r < 4; ++r) {
                int i = i0 + w * 16 + lg * 4 + r;
                float v = acc[u][r] + bias;
                unsigned short hh = f2bf(v);
                unsigned short ll = f2bf(v - bf2f(hh));
                if (u < 2) {
                    size_t off = ((size_t)b * NN + i) * CO + o;
                    q_hi[off] = hh; q_lo[off] = ll;
                } else {
                    size_t off = ((size_t)b * NN + i) * CO + (o - 32);
                    k_hi[off] = hh; k_lo[off] = ll;
                }
            }
        }
    } else {
        // ---- V projection, wave (w-4) -> c rows [(w-4)*64, +64) ----
        int cb = (w - 4) * 64;
        f4 acc[4][4];   // [u c-sub][t i-sub]
#pragma unroll
        for (int u = 0; u < 4; ++u) {
            f4 bias4;
#pragma unroll
            for (int r = 0; r < 4; ++r) bias4[r] = bv[cb + u * 16 + lg * 4 + r];
#pragma unroll
            for (int t = 0; t < 4; ++t) acc[u][t] = bias4;
        }
        for (int ks = 0; ks < 8; ++ks) {
            bf8 bfr[4];
#pragma unroll
            for (int t = 0; t < 4; ++t) {
                int i = t * 16 + lr;
                int kc = ks * 32 + lg * 8;
                f4 xa = *(const f4*)&xT[i * 256 + (((kc >> 2) ^ (i & 7)) << 2)];
                f4 xb = *(const f4*)&xT[i * 256 + ((((kc >> 2) + 1) ^ (i & 7)) << 2)];
#pragma unroll
                for (int e = 0; e < 8; ++e)
                    bfr[t][e] = (short)f2bf((e < 4) ? xa[e] : xb[e - 4]);
            }
#pragma unroll
            for (int u = 0; u < 4; ++u) {
                const float* wrow = wv + (size_t)(cb + u * 16 + lr) * CC + ks * 32 + lg * 8;
                bf8 afr;
#pragma unroll
                for (int e = 0; e < 8; ++e) afr[e] = (short)f2bf(wrow[e]);
#pragma unroll
                for (int t = 0; t < 4; ++t)
                    acc[u][t] = __builtin_amdgcn_mfma_f32_16x16x32_bf16(afr, bfr[t], acc[u][t], 0, 0, 0);
            }
        }
#pragma unroll
        for (int u = 0; u < 4; ++u)
#pragma unroll
            for (int t = 0; t < 4; ++t)
#pragma unroll
                for (int r = 0; r < 4; ++r) {
                    int c = cb + u * 16 + lg * 4 + r;
                    vws[((size_t)b * CC + c) * NN + i0 + t * 16 + lr] = f2bf(acc[u][t][r]);
                }
    }
}

// ---------------- kernel 2: flash attention + residual ----------------
// 512 blocks (2/CU), 8 waves. Block = (batch, 64q, 128c-half).
// Wave w = (qs=w>>2, js=(w>>1)&1, cs=w&1): S^T for its (32q, 32j) slice via
// 32x32x16 swapped QK^T (split precision), exp in-register, P assembled into
// PV B-fragments IN REGISTERS via a deterministic half-exchange:
//   send = hh ? plo : phi; recv = __shfl_xor(send,32);
//   u = {hh?recv:plo, hh?recv':plo', hh?phi:recv, hh?phi':recv'}
// (derived from the R8-verified reg->j map: r -> j = (r&3)+8*(r>>2)+4*hh).
// PV: A = V from LDS at column chunk (js*4 + kc*2 + hh)  [R12/13 bug: js*4
// was missing -> wrong V columns], B = P regs; wave covers 64c x 32q over its
// 32j; O partials summed across js in the LDS epilogue. K/V double-buffered
// via global_load_lds (swizzled source involution). ONE barrier/iter.
__global__ __launch_bounds__(512, 4) void k_attn(
        const unsigned short* __restrict__ q_hi, const unsigned short* __restrict__ q_lo,
        const unsigned short* __restrict__ k_hi, const unsigned short* __restrict__ k_lo,
        const unsigned short* __restrict__ vws,
        const float* __restrict__ x, float* __restrict__ out) {
    __shared__ __align__(16) unsigned short Vt[2][8192];   // [p][c128][slot8][8] 16KB each
    __shared__ __align__(16) unsigned short K2[2][4096];   // [p][j64][slot8][8] hi0-3/lo4-7
    __shared__ float lsum_s[2][2][32];                     // [qs][js][q]

    int m = blockIdx.x;
    int xcd = m & 7;                 // XCD pair {2b,2b+1} serves batch b
    int b = xcd >> 1;
    int t128 = ((m >> 3) << 1) + (xcd & 1);
    int qblk = t128 >> 1;            // 0..63
    int hc = t128 & 1;               // c-half
    int i0 = qblk * 64;
    int cb0 = hc * 128;
    int tid = threadIdx.x, w = tid >> 6, lane = tid & 63;
    int l31 = lane & 31, hh = lane >> 5;
    int qs = w >> 2, js = (w >> 1) & 1, cs = w & 1;

    // Q B-fragments (32x32x16): lane holds Q[q=i0+qs*32+l31][d = dc*16+hh*8+e]
    bf8 qfh0, qfl0, qfh1, qfl1;
    {
        size_t qoff = ((size_t)b * NN + i0 + qs * 32 + l31) * CO + hh * 8;
        qfh0 = *(const bf8*)(q_hi + qoff);
        qfl0 = *(const bf8*)(q_lo + qoff);
        qfh1 = *(const bf8*)(q_hi + qoff + 16);
        qfl1 = *(const bf8*)(q_lo + qoff + 16);
    }

    // stage sources (pre-swizzled involution: phys slot sl holds chunk sl^(row&7))
    int l3 = lane >> 3, sl = lane & 7;
    int us = sl ^ l3;
    const unsigned short* kbase = (us < 4) ? (k_hi + (size_t)b * NN * CO + us * 8)
                                           : (k_lo + (size_t)b * NN * CO + (us - 4) * 8);
    const unsigned short* ksrc = kbase + (size_t)(w * 8 + l3) * CO;
    const unsigned short* vsrc = vws + ((size_t)b * CC + cb0 + w * 16 + l3) * NN + us * 8;

    auto stageK = [&](int jt, int p) {
        int j0 = ((jt < 64) ? jt : 63) * 64;
        __builtin_amdgcn_global_load_lds((const AS1 void*)(ksrc + (size_t)j0 * CO),
            (AS3 void*)(&K2[p][(w * 8) * 64]), 16, 0, 0);
    };
    auto stageV = [&](int jt, int p) {
        int j0 = ((jt < 64) ? jt : 63) * 64;
#pragma unroll
        for (int n = 0; n < 2; ++n) {
            __builtin_amdgcn_global_load_lds((const AS1 void*)(vsrc + (size_t)(n * 8) * NN + j0),
                (AS3 void*)(&Vt[p][(w * 16 + n * 8) * 64]), 16, 0, 0);
        }
    };

    // read-offset precompute
    int krow = js * 32 + l31, ksw = krow & 7, koff = krow * 64;           // S A-frag
    int vrow0 = cs * 64 + l31,      vsw0 = vrow0 & 7, voff0 = vrow0 * 64; // PV A ct=0
    int vrow1 = cs * 64 + 32 + l31, vsw1 = vrow1 & 7, voff1 = vrow1 * 64; // PV A ct=1

    f16f acc0 = {}, acc1 = {};
    float lsum = 0.f;

    stageK(0, 0);
    stageV(0, 0);
    __builtin_amdgcn_sched_barrier(0);
    asm volatile("s_waitcnt vmcnt(0) lgkmcnt(0)" ::: "memory");
    __builtin_amdgcn_s_barrier();
    __builtin_amdgcn_sched_barrier(0);

    for (int jt = 0; jt < 64; ++jt) {
        int p = jt & 1;
        // stages for jt+1 issued first: full-iteration latency cover
        stageK(jt + 1, p ^ 1);
        stageV(jt + 1, p ^ 1);
        // ---- S^T = K·Q^T (32x32x16, split precision) ----
        const unsigned short* Kp = &K2[p][koff];
        f16f s = {};
        {
            bf8 kfh = *(const bf8*)(Kp + ((0 + hh) ^ ksw) * 8);
            bf8 kfl = *(const bf8*)(Kp + ((4 + hh) ^ ksw) * 8);
            s = __builtin_amdgcn_mfma_f32_32x32x16_bf16(kfh, qfl0, s, 0, 0, 0);
            s = __builtin_amdgcn_mfma_f32_32x32x16_bf16(kfl, qfh0, s, 0, 0, 0);
            s = __builtin_amdgcn_mfma_f32_32x32x16_bf16(kfh, qfh0, s, 0, 0, 0);
        }
        {
            bf8 kfh = *(const bf8*)(Kp + ((2 + hh) ^ ksw) * 8);
            bf8 kfl = *(const bf8*)(Kp + ((6 + hh) ^ ksw) * 8);
            s = __builtin_amdgcn_mfma_f32_32x32x16_bf16(kfh, qfl1, s, 0, 0, 0);
            s = __builtin_amdgcn_mfma_f32_32x32x16_bf16(kfl, qfh1, s, 0, 0, 0);
            s = __builtin_amdgcn_mfma_f32_32x32x16_bf16(kfh, qfh1, s, 0, 0, 0);
        }
        // ---- exp (in-register; lane (l31,hh) holds 16 j-rows, q=l31) ----
        float e0 = __expf(s[0]),  e1 = __expf(s[1]),  e2 = __expf(s[2]),  e3 = __expf(s[3]);
        float e4 = __expf(s[4]),  e5 = __expf(s[5]),  e6 = __expf(s[6]),  e7 = __expf(s[7]);
        float e8 = __expf(s[8]),  e9 = __expf(s[9]),  e10 = __expf(s[10]), e11 = __expf(s[11]);
        float e12 = __expf(s[12]), e13 = __expf(s[13]), e14 = __expf(s[14]), e15 = __expf(s[15]);
        lsum += ((e0 + e1) + (e2 + e3)) + ((e4 + e5) + (e6 + e7))
              + ((e8 + e9) + (e10 + e11)) + ((e12 + e13) + (e14 + e15));
        // ---- assemble B-fragments via deterministic half-exchange; PV ----
        __builtin_amdgcn_s_setprio(1);
        {
            // kc = 0: k = hh*8+e, j_rel = 0..15 (regs e0..e7)
            unsigned int plo0 = cvt_pk_bf16(e0, e1), plo1 = cvt_pk_bf16(e2, e3);
            unsigned int phi0 = cvt_pk_bf16(e4, e5), phi1 = cvt_pk_bf16(e6, e7);
            unsigned int s0 = hh ? plo0 : phi0;
            unsigned int s1 = hh ? plo1 : phi1;
            unsigned int r0 = __shfl_xor(s0, 32, 64);
            unsigned int r1 = __shfl_xor(s1, 32, 64);
            union { unsigned int u[4]; bf8 v; } pb;
            pb.u[0] = hh ? r0 : plo0;
            pb.u[1] = hh ? r1 : plo1;
            pb.u[2] = hh ? phi0 : r0;
            pb.u[3] = hh ? phi1 : r1;
            bf8 vf0 = *(const bf8*)&Vt[p][voff0 + (((js * 4 + 0 + hh) ^ vsw0)) * 8];
            bf8 vf1 = *(const bf8*)&Vt[p][voff1 + (((js * 4 + 0 + hh) ^ vsw1)) * 8];
            acc0 = __builtin_amdgcn_mfma_f32_32x32x16_bf16(vf0, pb.v, acc0, 0, 0, 0);
            acc1 = __builtin_amdgcn_mfma_f32_32x32x16_bf16(vf1, pb.v, acc1, 0, 0, 0);
        }
        {
            // kc = 1: j_rel = 16..31 (regs e8..e15)
            unsigned int plo0 = cvt_pk_bf16(e8, e9),   plo1 = cvt_pk_bf16(e10, e11);
            unsigned int phi0 = cvt_pk_bf16(e12, e13), phi1 = cvt_pk_bf16(e14, e15);
            unsigned int s0 = hh ? plo0 : phi0;
            unsigned int s1 = hh ? plo1 : phi1;
            unsigned int r0 = __shfl_xor(s0, 32, 64);
            unsigned int r1 = __shfl_xor(s1, 32, 64);
            union { unsigned int u[4]; bf8 v; } pb;
            pb.u[0] = hh ? r0 : plo0;
            pb.u[1] = hh ? r1 : plo1;
            pb.u[2] = hh ? phi0 : r0;
            pb.u[3] = hh ? phi1 : r1;
            bf8 vf0 = *(const bf8*)&Vt[p][voff0 + (((js * 4 + 2 + hh) ^ vsw0)) * 8];
            bf8 vf1 = *(const bf8*)&Vt[p][voff1 + (((js * 4 + 2 + hh) ^ vsw1)) * 8];
            acc0 = __builtin_amdgcn_mfma_f32_32x32x16_bf16(vf0, pb.v, acc0, 0, 0, 0);
            acc1 = __builtin_amdgcn_mfma_f32_32x32x16_bf16(vf1, pb.v, acc1, 0, 0, 0);
        }
        __builtin_amdgcn_s_setprio(0);
        // ---- ONE barrier: stages landed (vmcnt 0), K/V buffer reads done ----
        __builtin_amdgcn_sched_barrier(0);
        asm volatile("s_waitcnt vmcnt(0) lgkmcnt(0)" ::: "memory");
        __builtin_amdgcn_s_barrier();
        __builtin_amdgcn_sched_barrier(0);
    }

    // lsum: combine hh halves -> per-(qs,js) row sums; cs=0 wave publishes
    lsum += __shfl_xor(lsum, 32, 64);
    if (cs == 0 && lane < 32) lsum_s[qs][js][l31] = lsum;

    // O partial exchange across js (reuse Vt+K2 region as f32 scratch, 32 KB)
    float* VtF = (float*)&Vt[0][0];
    int pid = qs * 2 + cs;           // 0..3
    if (js == 1) {
#pragma unroll
        for (int r = 0; r < 16; ++r) {
            VtF[pid * 2048 + 0    + lane * 16 + r] = acc0[r];
            VtF[pid * 2048 + 1024 + lane * 16 + r] = acc1[r];
        }
    }
    __syncthreads();
    if (js == 0) {
        float linv = 1.0f / (lsum_s[qs][0][l31] + lsum_s[qs][1][l31]);
        int iq = i0 + qs * 32 + l31;
#pragma unroll
        for (int r = 0; r < 16; ++r) {
            int c0 = cb0 + cs * 64 + (r & 3) + 8 * (r >> 2) + 4 * hh;
            size_t off0 = ((size_t)(b * CC + c0)) * NN + iq;
            out[off0] = (acc0[r] + VtF[pid * 2048 + lane * 16 + r]) * linv + x[off0];
            size_t off1 = ((size_t)(b * CC + c0 + 32)) * NN + iq;
            out[off1] = (acc1[r] + VtF[pid * 2048 + 1024 + lane * 16 + r]) * linv + x[off1];
        }
    }
}

extern "C" void kernel_launch(void* const* d_in, const int* in_sizes, int n_in,
                              void* d_out, int out_size, void* d_ws, size_t ws_size,
                              hipStream_t stream) {
    const float* x  = (const float*)d_in[0];
    const float* wq = (const float*)d_in[1];
    const float* bq = (const float*)d_in[2];
    const float* wk = (const float*)d_in[3];
    const float* bk = (const float*)d_in[4];
    const float* wv = (const float*)d_in[5];
    const float* bv = (const float*)d_in[6];
    float* out = (float*)d_out;
    char* ws = (char*)d_ws;
    // ws: qh 1MB | ql 1MB | kh 1MB | kl 1MB | v 8MB
    unsigned short* qh = (unsigned short*)(ws);
    unsigned short* ql = (unsigned short*)(ws + 1048576);
    unsigned short* kh = (unsigned short*)(ws + 2097152);
    unsigned short* kl = (unsigned short*)(ws + 3145728);
    unsigned short* vv = (unsigned short*)(ws + 4194304);

    hipLaunchKernelGGL(k_prep, dim3(256), dim3(512), 0, stream,
                       x, wq, bq, wk, bk, wv, bv, qh, ql, kh, kl, vv);
    hipLaunchKernelGGL(k_attn, dim3(512), dim3(512), 0, stream,
                       qh, ql, kh, kl, vv, x, out);
}

// Round 15
// 102.537 us; speedup vs baseline: 1.2356x; 1.2356x over previous
//
#include <hip/hip_runtime.h>
#include <cstdint>
#include <cstddef>

#define BB 4
#define CC 256
#define NN 4096
#define CO 32

typedef __attribute__((ext_vector_type(8))) short bf8;
typedef __attribute__((ext_vector_type(4))) float f4;
typedef __attribute__((ext_vector_type(16))) float f16f;
typedef __attribute__((ext_vector_type(2))) unsigned int u32x2;

#define AS1 __attribute__((address_space(1)))
#define AS3 __attribute__((address_space(3)))

__device__ __forceinline__ unsigned short f2bf(float f) {
    union { float f; unsigned int u; } c; c.f = f;
    unsigned int r = c.u + 0x7FFFu + ((c.u >> 16) & 1u);
    return (unsigned short)(r >> 16);
}
__device__ __forceinline__ float bf2f(unsigned short b) {
    union { unsigned int u; float f; } c; c.u = ((unsigned int)b) << 16;
    return c.f;
}
__device__ __forceinline__ unsigned int cvt_pk_bf16(float a, float b) {
    unsigned int r;
    asm("v_cvt_pk_bf16_f32 %0, %1, %2" : "=v"(r) : "v"(a), "v"(b));
    return r;
}

// full window barrier: stages issued at window top drain here
#define FULL_BARRIER()                                          \
    do {                                                        \
        __builtin_amdgcn_sched_barrier(0);                      \
        asm volatile("s_waitcnt vmcnt(0) lgkmcnt(0)" ::: "memory"); \
        __builtin_amdgcn_s_barrier();                           \
        __builtin_amdgcn_sched_barrier(0);                      \
    } while (0)

// ---------------- kernel 1: fused prep (transpose + QK-proj + V-proj) -------
__global__ __launch_bounds__(512, 2) void k_prep(
        const float* __restrict__ x,
        const float* __restrict__ wq, const float* __restrict__ bq,
        const float* __restrict__ wk, const float* __restrict__ bk,
        const float* __restrict__ wv, const float* __restrict__ bv,
        unsigned short* __restrict__ q_hi, unsigned short* __restrict__ q_lo,
        unsigned short* __restrict__ k_hi, unsigned short* __restrict__ k_lo,
        unsigned short* __restrict__ vws) {
    __shared__ float xT[64 * 256];   // (i,c) at i*256 + ((c>>2)^(i&7))*4 + (c&3)
    int blk = blockIdx.x;
    int it = blk & 63, b = blk >> 6;
    int i0 = it * 64;
    int tid = threadIdx.x, w = tid >> 6, lane = tid & 63;
    int lr = lane & 15, lg = lane >> 4;

    // phase 1: load + swizzled transpose
    {
        const float* xp = x + (size_t)b * CC * NN + i0;
        int cl = tid >> 4;            // 0..31
        int il = (tid & 15) * 4;      // 0..60
#pragma unroll
        for (int pass = 0; pass < 8; ++pass) {
            int c = pass * 32 + cl;
            f4 v = *(const f4*)(xp + (size_t)c * NN + il);
#pragma unroll
            for (int jj = 0; jj < 4; ++jj) {
                int i = il + jj;
                xT[i * 256 + (((c >> 2) ^ (i & 7)) << 2) + (c & 3)] = v[jj];
            }
        }
    }
    __syncthreads();

    if (w < 4) {
        // ---- Q/K projection, wave w -> local i rows [w*16, w*16+16) ----
        f4 acc[4] = {};
        for (int ks = 0; ks < 8; ++ks) {
            int i = w * 16 + lr;
            int kc = ks * 32 + lg * 8;
            f4 xa = *(const f4*)&xT[i * 256 + (((kc >> 2) ^ (i & 7)) << 2)];
            f4 xb = *(const f4*)&xT[i * 256 + ((((kc >> 2) + 1) ^ (i & 7)) << 2)];
            bf8 ahi, alo;
#pragma unroll
            for (int e = 0; e < 8; ++e) {
                float f = (e < 4) ? xa[e] : xb[e - 4];
                unsigned short hh = f2bf(f);
                ahi[e] = (short)hh;
                alo[e] = (short)f2bf(f - bf2f(hh));
            }
#pragma unroll
            for (int u = 0; u < 4; ++u) {
                int o = u * 16 + lr;
                const float* wrow = (u < 2) ? (wq + (size_t)o * CC)
                                            : (wk + (size_t)(o - 32) * CC);
                bf8 bhi, blo;
#pragma unroll
                for (int e = 0; e < 8; ++e) {
                    float wvv = wrow[ks * 32 + lg * 8 + e];
                    unsigned short hh = f2bf(wvv);
                    bhi[e] = (short)hh;
                    blo[e] = (short)f2bf(wvv - bf2f(hh));
                }
                acc[u] = __builtin_amdgcn_mfma_f32_16x16x32_bf16(alo, bhi, acc[u], 0, 0, 0);
                acc[u] = __builtin_amdgcn_mfma_f32_16x16x32_bf16(ahi, blo, acc[u], 0, 0, 0);
                acc[u] = __builtin_amdgcn_mfma_f32_16x16x32_bf16(ahi, bhi, acc[u], 0, 0, 0);
            }
        }
#pragma unroll
        for (int u = 0; u < 4; ++u) {
            int o = u * 16 + lr;
            float bias = (u < 2) ? bq[o] : bk[o - 32];
#pragma unroll
            for (int r = 0; r < 4; ++r) {
                int i = i0 + w * 16 + lg * 4 + r;
                float v = acc[u][r] + bias;
                unsigned short hh = f2bf(v);
                unsigned short ll = f2bf(v - bf2f(hh));
                if (u < 2) {
                    size_t off = ((size_t)b * NN + i) * CO + o;
                    q_hi[off] = hh; q_lo[off] = ll;
                } else {
                    size_t off = ((size_t)b * NN + i) * CO + (o - 32);
                    k_hi[off] = hh; k_lo[off] = ll;
                }
            }
        }
    } else {
        // ---- V projection, wave (w-4) -> c rows [(w-4)*64, +64) ----
        int cb = (w - 4) * 64;
        f4 acc[4][4];   // [u c-sub][t i-sub]
#pragma unroll
        for (int u = 0; u < 4; ++u) {
            f4 bias4;
#pragma unroll
            for (int r = 0; r < 4; ++r) bias4[r] = bv[cb + u * 16 + lg * 4 + r];
#pragma unroll
            for (int t = 0; t < 4; ++t) acc[u][t] = bias4;
        }
        for (int ks = 0; ks < 8; ++ks) {
            bf8 bfr[4];
#pragma unroll
            for (int t = 0; t < 4; ++t) {
                int i = t * 16 + lr;
                int kc = ks * 32 + lg * 8;
                f4 xa = *(const f4*)&xT[i * 256 + (((kc >> 2) ^ (i & 7)) << 2)];
                f4 xb = *(const f4*)&xT[i * 256 + ((((kc >> 2) + 1) ^ (i & 7)) << 2)];
#pragma unroll
                for (int e = 0; e < 8; ++e)
                    bfr[t][e] = (short)f2bf((e < 4) ? xa[e] : xb[e - 4]);
            }
#pragma unroll
            for (int u = 0; u < 4; ++u) {
                const float* wrow = wv + (size_t)(cb + u * 16 + lr) * CC + ks * 32 + lg * 8;
                bf8 afr;
#pragma unroll
                for (int e = 0; e < 8; ++e) afr[e] = (short)f2bf(wrow[e]);
#pragma unroll
                for (int t = 0; t < 4; ++t)
                    acc[u][t] = __builtin_amdgcn_mfma_f32_16x16x32_bf16(afr, bfr[t], acc[u][t], 0, 0, 0);
            }
        }
#pragma unroll
        for (int u = 0; u < 4; ++u)
#pragma unroll
            for (int t = 0; t < 4; ++t)
#pragma unroll
                for (int r = 0; r < 4; ++r) {
                    int c = cb + u * 16 + lg * 4 + r;
                    vws[((size_t)b * CC + c) * NN + i0 + t * 16 + lr] = f2bf(acc[u][t][r]);
                }
    }
}

// ---------------- kernel 2: flash attention + residual ----------------
// 512 blocks (2/CU), 8 waves. Block = (batch, 64q, 128c-half).
// Producer/consumer wave split, ONE barrier per window:
//   waves 0-3 (S): wave a computes S^T for q-rows [a*16,+16) x ALL 64 j via
//     swapped 16x16 split-precision QK^T (R7 frag reads), in-register exp,
//     P -> Pt[(jt+1)&1] with R10's verified write swizzle.
//   waves 4-7 (PV): wave cw accumulates O^T for c [cw*32,+32) x 64q via
//     32x32x16 (R10's verified P-read pattern + R7's V involution),
//     reading Pt[jt&1], Vt[jt&1].
// Window jt: [barrier] stage V(jt+1)->Vt[(jt+1)&1], K(jt+2)->K2[jt&1];
//            S(jt+1) writes Pt[(jt+1)&1]; PV(jt) reads Pt[jt&1]/Vt[jt&1].
// All cross-window hazards barrier-separated (vmcnt(0)+lgkmcnt(0)).
__global__ __launch_bounds__(512, 4) void k_attn(
        const unsigned short* __restrict__ q_hi, const unsigned short* __restrict__ q_lo,
        const unsigned short* __restrict__ k_hi, const unsigned short* __restrict__ k_lo,
        const unsigned short* __restrict__ vws,
        const float* __restrict__ x, float* __restrict__ out) {
    __shared__ __align__(16) unsigned short Vt[2][8192];   // [p][c128][slot8][8] 16KB each
    __shared__ __align__(16) unsigned short K2[2][4096];   // [p][j64][slot8][8] hi0-3/lo4-7
    __shared__ __align__(16) unsigned short Pt[2][4096];   // [p][q64][slot8][8] 8KB each
    __shared__ float linv_s[64];

    int m = blockIdx.x;
    int xcd = m & 7;                 // XCD pair {2b,2b+1} serves batch b
    int b = xcd >> 1;
    int t128 = ((m >> 3) << 1) + (xcd & 1);
    int qblk = t128 >> 1;            // 0..63
    int hc = t128 & 1;               // c-half
    int i0 = qblk * 64;
    int cb0 = hc * 128;
    int tid = threadIdx.x, w = tid >> 6, lane = tid & 63;
    int lr = lane & 15, lg = lane >> 4, lr7 = lr & 7;
    int l31 = lane & 31, hh = lane >> 5;
    int a = w & 3;                   // S role: q-tile (w<4)
    int cw = w & 3;                  // PV role: c-slice (w>=4)

    // Q fragments (S waves): lane holds Q[q = i0+a*16+lr][d = lg*8+e]
    bf8 qfh = {}, qfl = {};
    if (w < 4) {
        size_t off = ((size_t)b * NN + i0 + a * 16 + lr) * CO + lg * 8;
        qfh = *(const bf8*)(q_hi + off);
        qfl = *(const bf8*)(q_lo + off);
    }

    // stage sources (pre-swizzled involution: phys slot sl holds chunk sl^(row&7))
    int l3 = lane >> 3, sl = lane & 7;
    int us = sl ^ l3;
    const unsigned short* kbase = (us < 4) ? (k_hi + (size_t)b * NN * CO + us * 8)
                                           : (k_lo + (size_t)b * NN * CO + (us - 4) * 8);
    const unsigned short* ksrc = kbase + (size_t)(w * 8 + l3) * CO;
    const unsigned short* vsrc = vws + ((size_t)b * CC + cb0 + w * 16 + l3) * NN + us * 8;

    auto stageK = [&](int jt, int p) {
        int j0 = ((jt < 64) ? jt : 63) * 64;
        __builtin_amdgcn_global_load_lds((const AS1 void*)(ksrc + (size_t)j0 * CO),
            (AS3 void*)(&K2[p][(w * 8) * 64]), 16, 0, 0);
    };
    auto stageV = [&](int jt, int p) {
        int j0 = ((jt < 64) ? jt : 63) * 64;
#pragma unroll
        for (int n = 0; n < 2; ++n) {
            __builtin_amdgcn_global_load_lds((const AS1 void*)(vsrc + (size_t)(n * 8) * NN + j0),
                (AS3 void*)(&Vt[p][(w * 16 + n * 8) * 64]), 16, 0, 0);
        }
    };

    f16f accA = {}, accB = {};       // PV waves: O^T 32c x {q-tile 0, q-tile 1}
    float lsum = 0.f;                // S waves

    // S(js): reads K2[js&1], writes Pt[js&1]; q-rows a*16+lr, all 64 j
    auto S_phase = [&](int js) {
        int pk = js & 1;
        int row = a * 16 + lr;
        int swz = (row ^ (row >> 3)) & 7;
#pragma unroll
        for (int t = 0; t < 4; ++t) {
            int jl = t * 16 + lr;
            const unsigned short* Kp = &K2[pk][jl * 64];
            bf8 kfh = *(const bf8*)(Kp + ((lg ^ lr7)) * 8);
            bf8 kfl = *(const bf8*)(Kp + (((4 | lg) ^ lr7)) * 8);
            f4 s = {};
            s = __builtin_amdgcn_mfma_f32_16x16x32_bf16(kfh, qfl, s, 0, 0, 0);
            s = __builtin_amdgcn_mfma_f32_16x16x32_bf16(kfl, qfh, s, 0, 0, 0);
            s = __builtin_amdgcn_mfma_f32_16x16x32_bf16(kfh, qfh, s, 0, 0, 0);
            float e0 = __expf(s[0]), e1 = __expf(s[1]), e2 = __expf(s[2]), e3 = __expf(s[3]);
            lsum += (e0 + e1) + (e2 + e3);
            u32x2 d;
            d[0] = cvt_pk_bf16(e0, e1);
            d[1] = cvt_pk_bf16(e2, e3);
            int slot = (t * 2 + (lg >> 1)) ^ swz;
            *(u32x2*)&Pt[pk][row * 64 + slot * 8 + (lg & 1) * 4] = d;
        }
    };
    // PV(jt): 32c x 64q, full 64-j contraction; A = V (LDS), B = P (LDS)
    auto PV_phase = [&](int jt) {
        int pv = jt & 1;
        int vr = cw * 32 + l31, vsw = vr & 7;
        const unsigned short* Vr = &Vt[pv][vr * 64];
        int pr0 = l31,       psw0 = (pr0 ^ (pr0 >> 3)) & 7;
        int pr1 = 32 + l31,  psw1 = (pr1 ^ (pr1 >> 3)) & 7;
        const unsigned short* Pr0 = &Pt[pv][pr0 * 64];
        const unsigned short* Pr1 = &Pt[pv][pr1 * 64];
#pragma unroll
        for (int kc = 0; kc < 4; ++kc) {
            int ch = kc * 2 + hh;
            bf8 vf  = *(const bf8*)(Vr  + ((ch ^ vsw))  * 8);
            bf8 pb0 = *(const bf8*)(Pr0 + ((ch ^ psw0)) * 8);
            bf8 pb1 = *(const bf8*)(Pr1 + ((ch ^ psw1)) * 8);
            accA = __builtin_amdgcn_mfma_f32_32x32x16_bf16(vf, pb0, accA, 0, 0, 0);
            accB = __builtin_amdgcn_mfma_f32_32x32x16_bf16(vf, pb1, accB, 0, 0, 0);
        }
    };

    // prologue: stage V(0),K(0); drain; window P0: stage K(1), S(0)
    stageK(0, 0);
    stageV(0, 0);
    FULL_BARRIER();
    stageK(1, 1);
    if (w < 4) S_phase(0);

    for (int jt = 0; jt < 64; ++jt) {
        FULL_BARRIER();              // Pt[jt&1], Vt[jt&1], K2[(jt+1)&1] ready
        stageV(jt + 1, (jt + 1) & 1);
        stageK(jt + 2, jt & 1);
        if (w < 4) {
            if (jt < 63) S_phase(jt + 1);
        } else {
            __builtin_amdgcn_s_setprio(1);
            PV_phase(jt);
            __builtin_amdgcn_s_setprio(0);
        }
    }

    // S waves: finish lsum (reduce over lg groups), publish 1/lsum
    if (w < 4) {
        lsum += __shfl_xor(lsum, 16, 64);
        lsum += __shfl_xor(lsum, 32, 64);
        if (lane < 16) linv_s[a * 16 + lane] = 1.0f / lsum;
    }
    __syncthreads();

    // PV waves: scale + residual + store (32x32 C/D: col q = l31, row c per reg)
    if (w >= 4) {
#pragma unroll
        for (int qt = 0; qt < 2; ++qt) {
            const f16f& ac = qt ? accB : accA;
            int qloc = qt * 32 + l31;
            float linv = linv_s[qloc];
            int iq = i0 + qloc;
#pragma unroll
            for (int r = 0; r < 16; ++r) {
                int c = cb0 + cw * 32 + (r & 3) + 8 * (r >> 2) + 4 * hh;
                size_t off = ((size_t)(b * CC + c)) * NN + iq;
                out[off] = ac[r] * linv + x[off];
            }
        }
    }
}

extern "C" void kernel_launch(void* const* d_in, const int* in_sizes, int n_in,
                              void* d_out, int out_size, void* d_ws, size_t ws_size,
                              hipStream_t stream) {
    const float* x  = (const float*)d_in[0];
    const float* wq = (const float*)d_in[1];
    const float* bq = (const float*)d_in[2];
    const float* wk = (const float*)d_in[3];
    const float* bk = (const float*)d_in[4];
    const float* wv = (const float*)d_in[5];
    const float* bv = (const float*)d_in[6];
    float* out = (float*)d_out;
    char* ws = (char*)d_ws;
    // ws: qh 1MB | ql 1MB | kh 1MB | kl 1MB | v 8MB
    unsigned short* qh = (unsigned short*)(ws);
    unsigned short* ql = (unsigned short*)(ws + 1048576);
    unsigned short* kh = (unsigned short*)(ws + 2097152);
    unsigned short* kl = (unsigned short*)(ws + 3145728);
    unsigned short* vv = (unsigned short*)(ws + 4194304);

    hipLaunchKernelGGL(k_prep, dim3(256), dim3(512), 0, stream,
                       x, wq, bq, wk, bk, wv, bv, qh, ql, kh, kl, vv);
    hipLaunchKernelGGL(k_attn, dim3(512), dim3(512), 0, stream,
                       qh, ql, kh, kl, vv, x, out);
}